// Round 1
// baseline (22999.670 us; speedup 1.0000x reference)
//
#include <hip/hip_runtime.h>
#include <cmath>

#define NB 32
#define NS 1024
#define NI 128
#define NH 1024
#define NO 64

// Persistent ESN kernel: 256 blocks (1/CU) x 256 threads.
//   blockIdx & 7  -> batch group bg (4 batches)  [round-robin => XCD-local]
//   blockIdx >> 3 -> row slice rs (32 rows of h) and output cols [2rs, 2rs+2)
// Per step: h_new = tanh(W_res.h + W_in.x_s) distributed over bg's 32 blocks;
// agent-scope spin barrier per bg; then each block reloads the full h (16KB)
// for its 4 batches (feeds next step's GEMV and this step's readout).
// W_res/W_in/W_out slices live entirely in VGPRs (zero per-step W traffic).

extern "C" __global__ void __launch_bounds__(256, 1)
esn_persistent(const float* __restrict__ x,
               const float* __restrict__ W_res,
               const float* __restrict__ W_in,
               const float* __restrict__ W_out_w,
               const float* __restrict__ W_out_b,
               float* __restrict__ out,
               unsigned char* ws)
{
    const int tid  = threadIdx.x;
    const int lane = tid & 63;
    const int wv   = tid >> 6;
    const int bg   = (int)blockIdx.x & 7;
    const int rs   = (int)blockIdx.x >> 3;
    const int rt   = tid & 7;    // row tile (4 rows)
    const int kid  = tid >> 3;   // k-chunk [kid*32, kid*32+32)
    const int r0   = rs * 32 + rt * 4;
    const int k0   = kid * 32;
    const int o0   = rs * 2;

    unsigned int* cnt = (unsigned int*)ws + bg * 32;   // one 128B line per bg
    float* h_buf = (float*)(ws + 4096);                // [2][NB][NH]

    __shared__ float4 h4[1055];          // h (4 batches), padded slot(k)=k+(k>>5)
    __shared__ float4 xl4[128];          // x_s (4 batches) [bb*32 + i/4]
    __shared__ float4 redA[4 * 8 * 4];   // [wave][rt][rr] -> float4 over bb
    __shared__ float  red2[4][8][2][4];  // readout partials

    // ---- one-time register loads ----
    float w_r[4][32];                    // W_res[r0+rr][k0+kk]
#pragma unroll
    for (int rr = 0; rr < 4; ++rr) {
        const float* wp = W_res + (r0 + rr) * NH + k0;
#pragma unroll
        for (int q = 0; q < 8; ++q) {
            float4 v = *(const float4*)(wp + q * 4);
            w_r[rr][q * 4 + 0] = v.x;
            w_r[rr][q * 4 + 1] = v.y;
            w_r[rr][q * 4 + 2] = v.z;
            w_r[rr][q * 4 + 3] = v.w;
        }
    }
    float4 w_i[4];                       // W_in[r0+rr][kid*4 .. +4)
#pragma unroll
    for (int rr = 0; rr < 4; ++rr)
        w_i[rr] = *(const float4*)(W_in + (r0 + rr) * NI + kid * 4);
    float w_o[2][4];                     // W_out_w[o0+o][tid + it*256]
#pragma unroll
    for (int it = 0; it < 4; ++it) {
        w_o[0][it] = W_out_w[(o0 + 0) * NH + tid + it * 256];
        w_o[1][it] = W_out_w[(o0 + 1) * NH + tid + it * 256];
    }
    const float bias = W_out_b[o0 + ((tid >> 2) & 1)];

    const float* xrow = x + ((bg * 4 + (tid >> 6)) * NS) * NI + (tid & 63) * 2;
    float* outb = out + (bg * 4) * (NS * NO);

    float2 xstash = *(const float2*)(xrow);   // prefetch x_0

    for (int s = 0; s < NS; ++s) {
        // stage x_s from the prefetch register
        ((float2*)xl4)[(tid >> 6) * 64 + (tid & 63)] = xstash;
        __syncthreads();                                   // A
        {   // prefetch x_{s+1}; completes under compute phase
            int sn = (s + 1 < NS) ? s + 1 : s;
            xstash = *(const float2*)(xrow + sn * NI);
        }

        float acc[4][4];
#pragma unroll
        for (int rr = 0; rr < 4; ++rr)
#pragma unroll
            for (int bb = 0; bb < 4; ++bb) acc[rr][bb] = 0.f;

        {   // u = W_in . x_s   (i-range [kid*4, kid*4+4))
            float4 xv[4];
#pragma unroll
            for (int bb = 0; bb < 4; ++bb) xv[bb] = xl4[bb * 32 + kid];
#pragma unroll
            for (int rr = 0; rr < 4; ++rr) {
#pragma unroll
                for (int bb = 0; bb < 4; ++bb) {
                    float v = acc[rr][bb];
                    v = fmaf(w_i[rr].x, xv[bb].x, v);
                    v = fmaf(w_i[rr].y, xv[bb].y, v);
                    v = fmaf(w_i[rr].z, xv[bb].z, v);
                    v = fmaf(w_i[rr].w, xv[bb].w, v);
                    acc[rr][bb] = v;
                }
            }
        }
        if (s != 0) {   // W_res . h_{s-1}  (k-range [k0, k0+32))
            const float4* hp = &h4[k0 + kid];   // padded base; imm offsets below
#pragma unroll
            for (int kk = 0; kk < 32; ++kk) {
                float4 hv = hp[kk];
#pragma unroll
                for (int rr = 0; rr < 4; ++rr) {
                    float w = w_r[rr][kk];
                    acc[rr][0] = fmaf(w, hv.x, acc[rr][0]);
                    acc[rr][1] = fmaf(w, hv.y, acc[rr][1]);
                    acc[rr][2] = fmaf(w, hv.z, acc[rr][2]);
                    acc[rr][3] = fmaf(w, hv.w, acc[rr][3]);
                }
            }
        }
        // reduce over kid: in-wave (lane bits 3..5), then cross-wave via LDS
#pragma unroll
        for (int rr = 0; rr < 4; ++rr)
#pragma unroll
            for (int bb = 0; bb < 4; ++bb) {
                float v = acc[rr][bb];
                v += __shfl_xor(v, 8, 64);
                v += __shfl_xor(v, 16, 64);
                v += __shfl_xor(v, 32, 64);
                acc[rr][bb] = v;
            }
        if ((lane & 56) == 0) {
#pragma unroll
            for (int rr = 0; rr < 4; ++rr)
                redA[(wv * 8 + rt) * 4 + rr] =
                    make_float4(acc[rr][0], acc[rr][1], acc[rr][2], acc[rr][3]);
        }
        __syncthreads();                                   // B
        const int hsel = s & 1;
        if (tid < 128) {   // 128 outputs: rl = row in slice, bb = batch
            const int rl = tid & 31;
            const int bb = tid >> 5;
            const float* redF = (const float*)redA;
            const int base = ((rl >> 2) * 4 + (rl & 3)) * 4 + bb;
            float v = redF[base] + redF[128 + base] + redF[256 + base] + redF[384 + base];
            v = tanhf(v);
            h_buf[hsel * (NB * NH) + (bg * 4 + bb) * NH + rs * 32 + rl] = v;
        }
        if (wv < 2) __threadfence();    // flush h stores (storer waves only)
        __syncthreads();                                   // B2
        if (tid == 0) {
            __hip_atomic_fetch_add(cnt, 1u, __ATOMIC_RELEASE,
                                   __HIP_MEMORY_SCOPE_AGENT);
            const unsigned target = 32u * (unsigned)(s + 1);
            while (__hip_atomic_load(cnt, __ATOMIC_RELAXED,
                                     __HIP_MEMORY_SCOPE_AGENT) < target)
                __builtin_amdgcn_s_sleep(1);
        }
        __syncthreads();                                   // C
        __builtin_amdgcn_fence(__ATOMIC_ACQUIRE, "agent");

        // reload full h_s for our 4 batches -> LDS, readout folded in
        float ro[2][4] = {{0.f, 0.f, 0.f, 0.f}, {0.f, 0.f, 0.f, 0.f}};
        {
            const float* hb = h_buf + hsel * (NB * NH) + (bg * 4) * NH;
#pragma unroll
            for (int it = 0; it < 4; ++it) {
                const int k = tid + it * 256;
                float v0 = hb[k];
                float v1 = hb[NH + k];
                float v2 = hb[2 * NH + k];
                float v3 = hb[3 * NH + k];
                h4[k + (k >> 5)] = make_float4(v0, v1, v2, v3);
                ro[0][0] = fmaf(w_o[0][it], v0, ro[0][0]);
                ro[0][1] = fmaf(w_o[0][it], v1, ro[0][1]);
                ro[0][2] = fmaf(w_o[0][it], v2, ro[0][2]);
                ro[0][3] = fmaf(w_o[0][it], v3, ro[0][3]);
                ro[1][0] = fmaf(w_o[1][it], v0, ro[1][0]);
                ro[1][1] = fmaf(w_o[1][it], v1, ro[1][1]);
                ro[1][2] = fmaf(w_o[1][it], v2, ro[1][2]);
                ro[1][3] = fmaf(w_o[1][it], v3, ro[1][3]);
            }
        }
#pragma unroll
        for (int o = 0; o < 2; ++o)
#pragma unroll
            for (int bb = 0; bb < 4; ++bb) {
                float v = ro[o][bb];
                v += __shfl_xor(v, 1, 64);
                v += __shfl_xor(v, 2, 64);
                v += __shfl_xor(v, 4, 64);
                ro[o][bb] = v;
            }
        if ((lane & 7) == 0) {
#pragma unroll
            for (int o = 0; o < 2; ++o)
#pragma unroll
                for (int bb = 0; bb < 4; ++bb)
                    red2[wv][lane >> 3][o][bb] = ro[o][bb];
        }
        __syncthreads();                                   // DE (h4 + red2 ready)
        if (tid < 8) {
            const int o  = tid >> 2;
            const int bb = tid & 3;
            float v = bias;
#pragma unroll
            for (int ww = 0; ww < 4; ++ww)
#pragma unroll
                for (int g = 0; g < 8; ++g)
                    v += red2[ww][g][o][bb];
            outb[bb * (NS * NO) + s * NO + o0 + o] = v;
        }
    }
}

extern "C" void kernel_launch(void* const* d_in, const int* in_sizes, int n_in,
                              void* d_out, int out_size, void* d_ws, size_t ws_size,
                              hipStream_t stream)
{
    const float* x       = (const float*)d_in[0];
    const float* W_res   = (const float*)d_in[1];
    const float* W_in    = (const float*)d_in[2];
    const float* W_out_w = (const float*)d_in[3];
    const float* W_out_b = (const float*)d_in[4];
    float* out           = (float*)d_out;
    unsigned char* ws    = (unsigned char*)d_ws;

    hipMemsetAsync(d_ws, 0, 4096, stream);   // zero barrier counters (re-poisoned each call)

    void* args[] = {&x, &W_res, &W_in, &W_out_w, &W_out_b, &out, &ws};
    hipError_t err = hipLaunchCooperativeKernel((void*)esn_persistent,
                                                dim3(256), dim3(256),
                                                args, 0, stream);
    if (err != hipSuccess) {
        (void)hipGetLastError();
        // fallback: plain launch (1 small block per CU -> co-resident in practice)
        hipLaunchKernelGGL(esn_persistent, dim3(256), dim3(256), 0, stream,
                           x, W_res, W_in, W_out_w, W_out_b, out, ws);
    }
}

// Round 3
// 5184.513 us; speedup vs baseline: 4.4362x; 4.4362x over previous
//
#include <hip/hip_runtime.h>
#include <cmath>

#define NB 32
#define NS 1024
#define NI 128
#define NH 1024
#define NO 64

// Persistent ESN kernel: 256 blocks (1/CU) x 256 threads.
//   blockIdx & 7  -> batch group bg (4 batches)
//   blockIdx >> 3 -> row slice rs (32 rows of h) and output cols [2rs, 2rs+2)
// Per step: h_new = tanh(W_res.h + W_in.x_s) distributed over bg's 32 blocks.
// h exchange + barrier counter all use sc0 sc1 (LLC-coherent, bypass L1/L2):
// NO buffer_wbl2 / buffer_inv in the loop (round-1 killer: threadfence+acquire
// fence caused full per-step L2 writeback+invalidate -> 22.5us/step stall).

__device__ __forceinline__ float load_llc(const float* p) {
    float v;
    asm volatile("global_load_dword %0, %1, off sc0 sc1" : "=v"(v) : "v"(p));
    return v;   // NOT valid until a following s_waitcnt vmcnt(0) + sched_barrier
}

extern "C" __global__ void __launch_bounds__(256, 1)
esn_persistent(const float* __restrict__ x,
               const float* __restrict__ W_res,
               const float* __restrict__ W_in,
               const float* __restrict__ W_out_w,
               const float* __restrict__ W_out_b,
               float* __restrict__ out,
               unsigned char* ws)
{
    const int tid  = threadIdx.x;
    const int lane = tid & 63;
    const int wv   = tid >> 6;
    const int bg   = (int)blockIdx.x & 7;
    const int rs   = (int)blockIdx.x >> 3;
    const int rt   = tid & 7;    // row tile (4 rows)
    const int kid  = tid >> 3;   // k-chunk [kid*32, kid*32+32)
    const int r0   = rs * 32 + rt * 4;
    const int k0   = kid * 32;
    const int o0   = rs * 2;

    unsigned int* cnt = (unsigned int*)ws + bg * 32;   // one 128B line per bg
    float* h_buf = (float*)(ws + 4096);                // [2][NB][NH]

    __shared__ float4 h4[1055];          // h (4 batches), padded slot(k)=k+(k>>5)
    __shared__ float4 xl4[128];          // x_s (4 batches) [bb*32 + i/4]
    __shared__ float4 redA[4 * 8 * 4];   // [wave][rt][rr] -> float4 over bb
    __shared__ float  red2[4][8][2][4];  // readout partials

    // ---- one-time register loads ----
    float w_r[4][32];                    // W_res[r0+rr][k0+kk]
#pragma unroll
    for (int rr = 0; rr < 4; ++rr) {
        const float* wp = W_res + (r0 + rr) * NH + k0;
#pragma unroll
        for (int q = 0; q < 8; ++q) {
            float4 v = *(const float4*)(wp + q * 4);
            w_r[rr][q * 4 + 0] = v.x;
            w_r[rr][q * 4 + 1] = v.y;
            w_r[rr][q * 4 + 2] = v.z;
            w_r[rr][q * 4 + 3] = v.w;
        }
    }
    float4 w_i[4];                       // W_in[r0+rr][kid*4 .. +4)
#pragma unroll
    for (int rr = 0; rr < 4; ++rr)
        w_i[rr] = *(const float4*)(W_in + (r0 + rr) * NI + kid * 4);
    float w_o[2][4];                     // W_out_w[o0+o][tid + it*256]
#pragma unroll
    for (int it = 0; it < 4; ++it) {
        w_o[0][it] = W_out_w[(o0 + 0) * NH + tid + it * 256];
        w_o[1][it] = W_out_w[(o0 + 1) * NH + tid + it * 256];
    }
    const float bias = W_out_b[o0 + ((tid >> 2) & 1)];

    const float* xrow = x + ((bg * 4 + (tid >> 6)) * NS) * NI + (tid & 63) * 2;
    float* outb = out + (bg * 4) * (NS * NO);

    float2 xstash = *(const float2*)(xrow);   // prefetch x_0

    for (int s = 0; s < NS; ++s) {
        // stage x_s from the prefetch register
        ((float2*)xl4)[(tid >> 6) * 64 + (tid & 63)] = xstash;
        __syncthreads();                                   // A
        {   // prefetch x_{s+1}; completes under compute phase
            int sn = (s + 1 < NS) ? s + 1 : s;
            xstash = *(const float2*)(xrow + sn * NI);
        }

        float acc[4][4];
#pragma unroll
        for (int rr = 0; rr < 4; ++rr)
#pragma unroll
            for (int bb = 0; bb < 4; ++bb) acc[rr][bb] = 0.f;

        {   // u = W_in . x_s   (i-range [kid*4, kid*4+4))
            float4 xv[4];
#pragma unroll
            for (int bb = 0; bb < 4; ++bb) xv[bb] = xl4[bb * 32 + kid];
#pragma unroll
            for (int rr = 0; rr < 4; ++rr) {
#pragma unroll
                for (int bb = 0; bb < 4; ++bb) {
                    float v = acc[rr][bb];
                    v = fmaf(w_i[rr].x, xv[bb].x, v);
                    v = fmaf(w_i[rr].y, xv[bb].y, v);
                    v = fmaf(w_i[rr].z, xv[bb].z, v);
                    v = fmaf(w_i[rr].w, xv[bb].w, v);
                    acc[rr][bb] = v;
                }
            }
        }
        if (s != 0) {   // W_res . h_{s-1}  (k-range [k0, k0+32))
            const float4* hp = &h4[k0 + kid];   // padded base; imm offsets below
#pragma unroll
            for (int kk = 0; kk < 32; ++kk) {
                float4 hv = hp[kk];
#pragma unroll
                for (int rr = 0; rr < 4; ++rr) {
                    float w = w_r[rr][kk];
                    acc[rr][0] = fmaf(w, hv.x, acc[rr][0]);
                    acc[rr][1] = fmaf(w, hv.y, acc[rr][1]);
                    acc[rr][2] = fmaf(w, hv.z, acc[rr][2]);
                    acc[rr][3] = fmaf(w, hv.w, acc[rr][3]);
                }
            }
        }
        // reduce over kid: in-wave (lane bits 3..5), then cross-wave via LDS
#pragma unroll
        for (int rr = 0; rr < 4; ++rr)
#pragma unroll
            for (int bb = 0; bb < 4; ++bb) {
                float v = acc[rr][bb];
                v += __shfl_xor(v, 8, 64);
                v += __shfl_xor(v, 16, 64);
                v += __shfl_xor(v, 32, 64);
                acc[rr][bb] = v;
            }
        if ((lane & 56) == 0) {
#pragma unroll
            for (int rr = 0; rr < 4; ++rr)
                redA[(wv * 8 + rt) * 4 + rr] =
                    make_float4(acc[rr][0], acc[rr][1], acc[rr][2], acc[rr][3]);
        }
        __syncthreads();                                   // B
        const int hsel = s & 1;
        if (tid < 128) {   // 128 outputs: rl = row in slice, bb = batch
            const int rl = tid & 31;
            const int bb = tid >> 5;
            const float* redF = (const float*)redA;
            const int base = ((rl >> 2) * 4 + (rl & 3)) * 4 + bb;
            float v = redF[base] + redF[128 + base] + redF[256 + base] + redF[384 + base];
            v = tanhf(v);
            // store to LLC (sc0 sc1), then wait own store ack — no cache flush
            __hip_atomic_store(
                &h_buf[hsel * (NB * NH) + (bg * 4 + bb) * NH + rs * 32 + rl],
                v, __ATOMIC_RELAXED, __HIP_MEMORY_SCOPE_AGENT);
            asm volatile("s_waitcnt vmcnt(0)" ::: "memory");
        }
        __syncthreads();                                   // B2 (stores ack'd)
        if (tid == 0) {
            __hip_atomic_fetch_add(cnt, 1u, __ATOMIC_RELAXED,
                                   __HIP_MEMORY_SCOPE_AGENT);
            const unsigned target = 32u * (unsigned)(s + 1);
            while (__hip_atomic_load(cnt, __ATOMIC_RELAXED,
                                     __HIP_MEMORY_SCOPE_AGENT) < target) {}
        }
        __syncthreads();                                   // C
        __builtin_amdgcn_sched_barrier(0);

        // reload full h_s for our 4 batches via LLC loads; readout folded in
        const float* hb = h_buf + hsel * (NB * NH) + (bg * 4) * NH;
        float hv[4][4];                                    // [it][bb]
#pragma unroll
        for (int it = 0; it < 4; ++it) {
            const int k = tid + it * 256;
#pragma unroll
            for (int bb = 0; bb < 4; ++bb)
                hv[it][bb] = load_llc(hb + bb * NH + k);
        }
        asm volatile("s_waitcnt vmcnt(0)" ::: "memory");
        __builtin_amdgcn_sched_barrier(0);

        float ro[2][4] = {{0.f, 0.f, 0.f, 0.f}, {0.f, 0.f, 0.f, 0.f}};
#pragma unroll
        for (int it = 0; it < 4; ++it) {
            const int k = tid + it * 256;
            h4[k + (k >> 5)] = make_float4(hv[it][0], hv[it][1], hv[it][2], hv[it][3]);
#pragma unroll
            for (int o = 0; o < 2; ++o)
#pragma unroll
                for (int bb = 0; bb < 4; ++bb)
                    ro[o][bb] = fmaf(w_o[o][it], hv[it][bb], ro[o][bb]);
        }
#pragma unroll
        for (int o = 0; o < 2; ++o)
#pragma unroll
            for (int bb = 0; bb < 4; ++bb) {
                float v = ro[o][bb];
                v += __shfl_xor(v, 1, 64);
                v += __shfl_xor(v, 2, 64);
                v += __shfl_xor(v, 4, 64);
                ro[o][bb] = v;
            }
        if ((lane & 7) == 0) {
#pragma unroll
            for (int o = 0; o < 2; ++o)
#pragma unroll
                for (int bb = 0; bb < 4; ++bb)
                    red2[wv][lane >> 3][o][bb] = ro[o][bb];
        }
        __syncthreads();                                   // DE (h4 + red2 ready)
        if (tid < 8) {
            const int o  = tid >> 2;
            const int bb = tid & 3;
            float v = bias;
#pragma unroll
            for (int ww = 0; ww < 4; ++ww)
#pragma unroll
                for (int g = 0; g < 8; ++g)
                    v += red2[ww][g][o][bb];
            outb[bb * (NS * NO) + s * NO + o0 + o] = v;
        }
    }
}

extern "C" void kernel_launch(void* const* d_in, const int* in_sizes, int n_in,
                              void* d_out, int out_size, void* d_ws, size_t ws_size,
                              hipStream_t stream)
{
    const float* x       = (const float*)d_in[0];
    const float* W_res   = (const float*)d_in[1];
    const float* W_in    = (const float*)d_in[2];
    const float* W_out_w = (const float*)d_in[3];
    const float* W_out_b = (const float*)d_in[4];
    float* out           = (float*)d_out;
    unsigned char* ws    = (unsigned char*)d_ws;

    hipMemsetAsync(d_ws, 0, 4096, stream);   // zero barrier counters each call

    void* args[] = {&x, &W_res, &W_in, &W_out_w, &W_out_b, &out, &ws};
    hipError_t err = hipLaunchCooperativeKernel((void*)esn_persistent,
                                                dim3(256), dim3(256),
                                                args, 0, stream);
    if (err != hipSuccess) {
        (void)hipGetLastError();
        // fallback: plain launch (1 small block per CU -> co-resident in practice)
        hipLaunchKernelGGL(esn_persistent, dim3(256), dim3(256), 0, stream,
                           x, W_res, W_in, W_out_w, W_out_b, out, ws);
    }
}